// Round 1
// baseline (1370.981 us; speedup 1.0000x reference)
//
#include <hip/hip_runtime.h>

#define EPSV 1e-5f

// ============================================================
// Phase 1: input-to-hidden TCL3D (+LN in/out) for all (t,n).
// One block per tb = t*B + n, 256 threads.
//   x[tb,4096] -> wx[tb, g, 512]   (layout [t][n][g][512])
// Contraction via "contract slowest mode, write transposed":
//   [a,b,c] --a--> [b,c,p] --b--> [c,p,q] --c--> [p,q,r]
// ============================================================
__global__ __launch_bounds__(256) void wx_kernel(
    const float* __restrict__ x,
    const float* __restrict__ Wfa, const float* __restrict__ Wfb,
    const float* __restrict__ Wfc,
    const float* __restrict__ Wba, const float* __restrict__ Wbb,
    const float* __restrict__ Wbc,
    const float* __restrict__ lniw, const float* __restrict__ lnib,
    const float* __restrict__ lnow, const float* __restrict__ lnob,
    float* __restrict__ wxo)
{
    __shared__ float Xs[4096];
    __shared__ float S1[2048];
    __shared__ float S2[1024];
    __shared__ float faS[384], fbS[384], fcS[384];
    __shared__ float baS[24], bbS[24], bcS[24];
    __shared__ float red[16];

    const int tid  = threadIdx.x;
    const int wid  = tid >> 6, lane = tid & 63;
    const size_t tb = blockIdx.x;
    const float* xp = x + tb * 4096;

    float s = 0.f, s2 = 0.f;
    for (int i = tid; i < 4096; i += 256) {
        float v = xp[i];
        Xs[i] = v;
        s += v; s2 += v * v;
    }
    for (int i = tid; i < 384; i += 256) {
        faS[i] = Wfa[i]; fbS[i] = Wfb[i]; fcS[i] = Wfc[i];
    }
    if (tid < 24) { baS[tid] = Wba[tid]; bbS[tid] = Wbb[tid]; bcS[tid] = Wbc[tid]; }

    __syncthreads();
    #pragma unroll
    for (int off = 32; off > 0; off >>= 1) {
        s  += __shfl_down(s,  off);
        s2 += __shfl_down(s2, off);
    }
    if (lane == 0) { red[wid] = s; red[8 + wid] = s2; }
    __syncthreads();
    s  = red[0] + red[1] + red[2] + red[3];
    s2 = red[8] + red[9] + red[10] + red[11];
    {
        float mu  = s * (1.f / 4096.f);
        float var = fmaxf(s2 * (1.f / 4096.f) - mu * mu, 0.f);
        float rs  = rsqrtf(var + EPSV);
        for (int i = tid; i < 4096; i += 256) Xs[i] = (Xs[i] - mu) * rs;
    }
    __syncthreads();

    for (int g = 0; g < 3; ++g) {
        // ---- stage 1: contract a(16) -> S1[(b*16+c)*8+p]   (layout [b,c,p])
        {
            float acc[8] = {0,0,0,0,0,0,0,0};
            const int rest = tid;                      // b*16+c
            const float* lw = lniw + g * 4096;
            const float* lb = lnib + g * 4096;
            #pragma unroll
            for (int m = 0; m < 16; ++m) {
                float xv = fmaf(Xs[m*256 + rest], lw[m*256 + rest], lb[m*256 + rest]);
                #pragma unroll
                for (int q = 0; q < 8; ++q)
                    acc[q] = fmaf(xv, faS[(g*16 + m)*8 + q], acc[q]);
            }
            float4* o = (float4*)(S1 + rest * 8);
            o[0] = make_float4(acc[0], acc[1], acc[2], acc[3]);
            o[1] = make_float4(acc[4], acc[5], acc[6], acc[7]);
        }
        __syncthreads();
        // ---- stage 2: contract b(16) -> S2[(c*8+p)*8+q]    (layout [c,p,q])
        {
            float acc[4] = {0,0,0,0};
            const int rest = tid & 127;                // c*8+p
            const int qh = tid >> 7;                   // 0..1
            #pragma unroll
            for (int m = 0; m < 16; ++m) {
                float xv = S1[m*128 + rest];
                #pragma unroll
                for (int j = 0; j < 4; ++j)
                    acc[j] = fmaf(xv, fbS[(g*16 + m)*8 + qh*4 + j], acc[j]);
            }
            float4* o = (float4*)(S2 + rest * 8 + qh * 4);
            o[0] = make_float4(acc[0], acc[1], acc[2], acc[3]);
        }
        __syncthreads();
        // ---- stage 3: contract c(16) -> [p,q,r] + rank-1 bias (in regs)
        float v0, v1; int idx0;
        {
            float acc[2] = {0, 0};
            const int rest = tid & 63;                 // p*8+q
            const int rh = tid >> 6;                   // r = rh*2 + {0,1}
            #pragma unroll
            for (int m = 0; m < 16; ++m) {
                float xv = S2[m*64 + rest];
                #pragma unroll
                for (int j = 0; j < 2; ++j)
                    acc[j] = fmaf(xv, fcS[(g*16 + m)*8 + rh*2 + j], acc[j]);
            }
            const int p = rest >> 3, q = rest & 7;
            float bpq = baS[g*8 + p] * bbS[g*8 + q];
            v0 = acc[0] + bpq * bcS[g*8 + rh*2 + 0];
            v1 = acc[1] + bpq * bcS[g*8 + rh*2 + 1];
            idx0 = rest * 8 + rh * 2;
        }
        // ---- std over 512, lnout affine, store
        float t = v0 + v1, t2 = v0*v0 + v1*v1;
        __syncthreads();
        #pragma unroll
        for (int off = 32; off > 0; off >>= 1) {
            t  += __shfl_down(t,  off);
            t2 += __shfl_down(t2, off);
        }
        if (lane == 0) { red[wid] = t; red[8 + wid] = t2; }
        __syncthreads();
        t  = red[0] + red[1] + red[2] + red[3];
        t2 = red[8] + red[9] + red[10] + red[11];
        float mu  = t * (1.f / 512.f);
        float var = fmaxf(t2 * (1.f / 512.f) - mu * mu, 0.f);
        float rs  = rsqrtf(var + EPSV);
        float* wp = wxo + (tb * 3 + g) * 512;
        float2 lw2 = *(const float2*)(lnow + g*512 + idx0);
        float2 lb2 = *(const float2*)(lnob + g*512 + idx0);
        float2 o2;
        o2.x = fmaf((v0 - mu) * rs, lw2.x, lb2.x);
        o2.y = fmaf((v1 - mu) * rs, lw2.y, lb2.y);
        *(float2*)(wp + idx0) = o2;
        // next gate's S1 writes are ordered behind the reduce's barriers
    }
}

// ============================================================
// Phase 2: sequential GRU scan. One block per batch sample n.
// 4 waves: waves 0-2 = gates (wave-internal LDS pipeline,
// U-factors held in VGPRs), wave 3 = 2-deep wx prefetcher.
// 2 __syncthreads per step.
// ============================================================
__global__ __launch_bounds__(256, 1) void scan_kernel(
    const float* __restrict__ wx,     // [T*B, 3, 512]
    const float* __restrict__ h0,     // [B, 512]
    const float* __restrict__ Ufa, const float* __restrict__ Ufb,
    const float* __restrict__ Ufc,
    const float* __restrict__ Uba, const float* __restrict__ Ubb,
    const float* __restrict__ Ubc,
    const float* __restrict__ lniw, const float* __restrict__ lnib,
    const float* __restrict__ lnow, const float* __restrict__ lnob,
    float* __restrict__ out,          // [T*B, 512]
    int T, int B)
{
    const int n = blockIdx.x;
    const int tid = threadIdx.x, wid = tid >> 6, lane = tid & 63;

    __shared__ float hS[512];
    __shared__ float hgS[3][512];
    __shared__ float SaS[3][512];
    __shared__ float SbS[3][512];
    __shared__ float UhS[3][512];
    __shared__ float wxS[2][1536];

    for (int i = tid; i < 512;  i += 256) hS[i] = h0[n * 512 + i];
    for (int i = tid; i < 1536; i += 256) wxS[0][i] = wx[(size_t)n * 1536 + i];

    const int g = (wid < 3) ? wid : 0;
    float f1[8][8], f2[8][8], f3[8][8];
    float lnw[8], lnb[8], low[8], lob[8], ub[8];
    if (wid < 3) {
        #pragma unroll
        for (int m = 0; m < 8; ++m)
            #pragma unroll
            for (int q = 0; q < 8; ++q) {
                f1[m][q] = Ufa[g*64 + m*8 + q];
                f2[m][q] = Ufb[g*64 + m*8 + q];
                f3[m][q] = Ufc[g*64 + m*8 + q];
            }
        const int p_ = lane >> 3, q_ = lane & 7;
        const float bpq = Uba[g*8 + p_] * Ubb[g*8 + q_];
        #pragma unroll
        for (int k = 0; k < 8; ++k) {
            lnw[k] = lniw[g*512 + lane*8 + k];
            lnb[k] = lnib[g*512 + lane*8 + k];
            low[k] = lnow[g*512 + lane*8 + k];
            lob[k] = lnob[g*512 + lane*8 + k];
            ub[k]  = bpq * Ubc[g*8 + k];
        }
    }
    float4 pf[6];
    if (wid == 3 && T > 1) {
        const float4* src = (const float4*)(wx + ((size_t)1 * B + n) * 1536);
        #pragma unroll
        for (int j = 0; j < 6; ++j) pf[j] = src[j*64 + lane];
    }
    __syncthreads();

    for (int t = 0; t < T; ++t) {
        if (wid < 3) {
            // ---- std(h) + lnin affine -> hgS[g]  (wave-internal)
            float hv[8];
            #pragma unroll
            for (int k = 0; k < 8; ++k) hv[k] = hS[lane*8 + k];
            float s = 0.f, s2 = 0.f;
            #pragma unroll
            for (int k = 0; k < 8; ++k) { s += hv[k]; s2 += hv[k]*hv[k]; }
            #pragma unroll
            for (int off = 1; off < 64; off <<= 1) {
                s += __shfl_xor(s, off); s2 += __shfl_xor(s2, off);
            }
            const float mu = s * (1.f/512.f);
            const float rs = rsqrtf(fmaxf(s2 * (1.f/512.f) - mu*mu, 0.f) + EPSV);
            {
                float hg[8];
                #pragma unroll
                for (int k = 0; k < 8; ++k)
                    hg[k] = fmaf((hv[k]-mu)*rs, lnw[k], lnb[k]);
                float4* o = (float4*)(hgS[g] + lane*8);
                o[0] = make_float4(hg[0],hg[1],hg[2],hg[3]);
                o[1] = make_float4(hg[4],hg[5],hg[6],hg[7]);
            }
            // ---- stage 1 (contract d) -> SaS[g]  [e,f,p]
            {
                float a[8] = {0,0,0,0,0,0,0,0};
                #pragma unroll
                for (int m = 0; m < 8; ++m) {
                    float xv = hgS[g][m*64 + lane];
                    #pragma unroll
                    for (int q = 0; q < 8; ++q) a[q] = fmaf(xv, f1[m][q], a[q]);
                }
                float4* o = (float4*)(SaS[g] + lane*8);
                o[0] = make_float4(a[0],a[1],a[2],a[3]);
                o[1] = make_float4(a[4],a[5],a[6],a[7]);
            }
            // ---- stage 2 (contract e) -> SbS[g]  [f,p,q]
            {
                float a[8] = {0,0,0,0,0,0,0,0};
                #pragma unroll
                for (int m = 0; m < 8; ++m) {
                    float xv = SaS[g][m*64 + lane];
                    #pragma unroll
                    for (int q = 0; q < 8; ++q) a[q] = fmaf(xv, f2[m][q], a[q]);
                }
                float4* o = (float4*)(SbS[g] + lane*8);
                o[0] = make_float4(a[0],a[1],a[2],a[3]);
                o[1] = make_float4(a[4],a[5],a[6],a[7]);
            }
            // ---- stage 3 (contract f) -> [p,q,r] regs, +Ub, std, lnout -> UhS[g]
            {
                float a[8] = {0,0,0,0,0,0,0,0};
                #pragma unroll
                for (int m = 0; m < 8; ++m) {
                    float xv = SbS[g][m*64 + lane];
                    #pragma unroll
                    for (int r = 0; r < 8; ++r) a[r] = fmaf(xv, f3[m][r], a[r]);
                }
                float s = 0.f, s2 = 0.f;
                #pragma unroll
                for (int k = 0; k < 8; ++k) { a[k] += ub[k]; s += a[k]; s2 += a[k]*a[k]; }
                #pragma unroll
                for (int off = 1; off < 64; off <<= 1) {
                    s += __shfl_xor(s, off); s2 += __shfl_xor(s2, off);
                }
                const float mu = s * (1.f/512.f);
                const float rs = rsqrtf(fmaxf(s2 * (1.f/512.f) - mu*mu, 0.f) + EPSV);
                float u[8];
                #pragma unroll
                for (int k = 0; k < 8; ++k) u[k] = fmaf((a[k]-mu)*rs, low[k], lob[k]);
                float4* o = (float4*)(UhS[g] + lane*8);
                o[0] = make_float4(u[0],u[1],u[2],u[3]);
                o[1] = make_float4(u[4],u[5],u[6],u[7]);
            }
        } else {
            // ---- wave 3: land wx(t+1) into LDS, issue loads for wx(t+2)
            if (t + 1 < T) {
                float4* dst = (float4*)(wxS[(t+1) & 1]);
                #pragma unroll
                for (int j = 0; j < 6; ++j) dst[j*64 + lane] = pf[j];
            }
            if (t + 2 < T) {
                const float4* src = (const float4*)(wx + ((size_t)(t+2)*B + n) * 1536);
                #pragma unroll
                for (int j = 0; j < 6; ++j) pf[j] = src[j*64 + lane];
            }
        }
        __syncthreads();   // (a) UhS + wxS[t&1] visible to all waves
        {
            const int i = tid * 2;
            const float* wxb = wxS[t & 1];
            const float2 u0 = *(const float2*)(UhS[0] + i);
            const float2 u1 = *(const float2*)(UhS[1] + i);
            const float2 u2 = *(const float2*)(UhS[2] + i);
            const float2 w0 = *(const float2*)(wxb + i);
            const float2 w1 = *(const float2*)(wxb + 512 + i);
            const float2 w2 = *(const float2*)(wxb + 1024 + i);
            const float2 hp = *(const float2*)(hS + i);
            float2 hn;
            {
                const float r  = 1.f / (1.f + __expf(-(w0.x + u0.x)));
                const float z  = 1.f / (1.f + __expf(-(w1.x + u1.x)));
                const float e2 = __expf(2.f * (w2.x + r * u2.x));
                const float nn = 1.f - 2.f / (e2 + 1.f);   // tanh, saturation-safe
                hn.x = (1.f - z) * nn + z * hp.x;
            }
            {
                const float r  = 1.f / (1.f + __expf(-(w0.y + u0.y)));
                const float z  = 1.f / (1.f + __expf(-(w1.y + u1.y)));
                const float e2 = __expf(2.f * (w2.y + r * u2.y));
                const float nn = 1.f - 2.f / (e2 + 1.f);
                hn.y = (1.f - z) * nn + z * hp.y;
            }
            *(float2*)(hS + i) = hn;
            *(float2*)(out + ((size_t)t * B + n) * 512 + i) = hn;
        }
        __syncthreads();   // (b) hS stable before next step's std(h)
    }
}

extern "C" void kernel_launch(void* const* d_in, const int* in_sizes, int n_in,
                              void* d_out, int out_size, void* d_ws, size_t ws_size,
                              hipStream_t stream)
{
    const float* x    = (const float*)d_in[0];
    const float* h0   = (const float*)d_in[1];
    const float* Wfa  = (const float*)d_in[2];
    const float* Wfb  = (const float*)d_in[3];
    const float* Wfc  = (const float*)d_in[4];
    const float* Wba  = (const float*)d_in[5];
    const float* Wbb  = (const float*)d_in[6];
    const float* Wbc  = (const float*)d_in[7];
    const float* Wliw = (const float*)d_in[8];
    const float* Wlib = (const float*)d_in[9];
    const float* Wlow = (const float*)d_in[10];
    const float* Wlob = (const float*)d_in[11];
    const float* Ufa  = (const float*)d_in[12];
    const float* Ufb  = (const float*)d_in[13];
    const float* Ufc  = (const float*)d_in[14];
    const float* Uba  = (const float*)d_in[15];
    const float* Ubb  = (const float*)d_in[16];
    const float* Ubc  = (const float*)d_in[17];
    const float* Uliw = (const float*)d_in[18];
    const float* Ulib = (const float*)d_in[19];
    const float* Ulow = (const float*)d_in[20];
    const float* Ulob = (const float*)d_in[21];

    const int B = in_sizes[1] / 512;            // 16
    const int T = in_sizes[0] / (B * 4096);     // 512

    float* wxws = (float*)d_ws;                 // [T*B, 3, 512] = 50.3 MB scratch
    float* out  = (float*)d_out;

    wx_kernel<<<T * B, 256, 0, stream>>>(x, Wfa, Wfb, Wfc, Wba, Wbb, Wbc,
                                         Wliw, Wlib, Wlow, Wlob, wxws);
    scan_kernel<<<B, 256, 0, stream>>>(wxws, h0, Ufa, Ufb, Ufc, Uba, Ubb, Ubc,
                                       Uliw, Ulib, Ulow, Ulob, out, T, B);
}

// Round 2
// 1125.239 us; speedup vs baseline: 1.2184x; 1.2184x over previous
//
#include <hip/hip_runtime.h>

#define EPSV 1e-5f

// Pin a value into a VGPR: compiler may no longer rematerialize it from
// global memory (it believes the asm modified it).
#define KEEP(x) asm volatile("" : "+v"(x))

// DPP-based full-wave sum, result broadcast (valid in all lanes via readlane).
// row_ror 8/4/2/1 -> every lane holds its 16-row sum; bcast15+bcast31
// accumulate rows so lane 63 holds the 64-lane total.
#define DPP_XADD(v, ctrl)                                                  \
    v += __int_as_float(__builtin_amdgcn_update_dpp(                       \
        0, __float_as_int(v), ctrl, 0xF, 0xF, false))

__device__ __forceinline__ float wave_allsum(float v) {
    DPP_XADD(v, 0x128);   // row_ror:8
    DPP_XADD(v, 0x124);   // row_ror:4
    DPP_XADD(v, 0x122);   // row_ror:2
    DPP_XADD(v, 0x121);   // row_ror:1  -> row sums everywhere
    DPP_XADD(v, 0x142);   // row_bcast15 -> lanes16-31 & 48-63 have half sums
    DPP_XADD(v, 0x143);   // row_bcast31 -> lane 63 has the total
    return __int_as_float(__builtin_amdgcn_readlane(__float_as_int(v), 63));
}

// ============================================================
// Phase 1: input-to-hidden TCL3D (+LN in/out) for all (t,n).
// (unchanged from round 1 — ~100us, revisit after the scan)
// ============================================================
__global__ __launch_bounds__(256) void wx_kernel(
    const float* __restrict__ x,
    const float* __restrict__ Wfa, const float* __restrict__ Wfb,
    const float* __restrict__ Wfc,
    const float* __restrict__ Wba, const float* __restrict__ Wbb,
    const float* __restrict__ Wbc,
    const float* __restrict__ lniw, const float* __restrict__ lnib,
    const float* __restrict__ lnow, const float* __restrict__ lnob,
    float* __restrict__ wxo)
{
    __shared__ float Xs[4096];
    __shared__ float S1[2048];
    __shared__ float S2[1024];
    __shared__ float faS[384], fbS[384], fcS[384];
    __shared__ float baS[24], bbS[24], bcS[24];
    __shared__ float red[16];

    const int tid  = threadIdx.x;
    const int wid  = tid >> 6, lane = tid & 63;
    const size_t tb = blockIdx.x;
    const float* xp = x + tb * 4096;

    float s = 0.f, s2 = 0.f;
    for (int i = tid; i < 4096; i += 256) {
        float v = xp[i];
        Xs[i] = v;
        s += v; s2 += v * v;
    }
    for (int i = tid; i < 384; i += 256) {
        faS[i] = Wfa[i]; fbS[i] = Wfb[i]; fcS[i] = Wfc[i];
    }
    if (tid < 24) { baS[tid] = Wba[tid]; bbS[tid] = Wbb[tid]; bcS[tid] = Wbc[tid]; }

    __syncthreads();
    #pragma unroll
    for (int off = 32; off > 0; off >>= 1) {
        s  += __shfl_down(s,  off);
        s2 += __shfl_down(s2, off);
    }
    if (lane == 0) { red[wid] = s; red[8 + wid] = s2; }
    __syncthreads();
    s  = red[0] + red[1] + red[2] + red[3];
    s2 = red[8] + red[9] + red[10] + red[11];
    {
        float mu  = s * (1.f / 4096.f);
        float var = fmaxf(s2 * (1.f / 4096.f) - mu * mu, 0.f);
        float rs  = rsqrtf(var + EPSV);
        for (int i = tid; i < 4096; i += 256) Xs[i] = (Xs[i] - mu) * rs;
    }
    __syncthreads();

    for (int g = 0; g < 3; ++g) {
        {
            float acc[8] = {0,0,0,0,0,0,0,0};
            const int rest = tid;
            const float* lw = lniw + g * 4096;
            const float* lb = lnib + g * 4096;
            #pragma unroll
            for (int m = 0; m < 16; ++m) {
                float xv = fmaf(Xs[m*256 + rest], lw[m*256 + rest], lb[m*256 + rest]);
                #pragma unroll
                for (int q = 0; q < 8; ++q)
                    acc[q] = fmaf(xv, faS[(g*16 + m)*8 + q], acc[q]);
            }
            float4* o = (float4*)(S1 + rest * 8);
            o[0] = make_float4(acc[0], acc[1], acc[2], acc[3]);
            o[1] = make_float4(acc[4], acc[5], acc[6], acc[7]);
        }
        __syncthreads();
        {
            float acc[4] = {0,0,0,0};
            const int rest = tid & 127;
            const int qh = tid >> 7;
            #pragma unroll
            for (int m = 0; m < 16; ++m) {
                float xv = S1[m*128 + rest];
                #pragma unroll
                for (int j = 0; j < 4; ++j)
                    acc[j] = fmaf(xv, fbS[(g*16 + m)*8 + qh*4 + j], acc[j]);
            }
            float4* o = (float4*)(S2 + rest * 8 + qh * 4);
            o[0] = make_float4(acc[0], acc[1], acc[2], acc[3]);
        }
        __syncthreads();
        float v0, v1; int idx0;
        {
            float acc[2] = {0, 0};
            const int rest = tid & 63;
            const int rh = tid >> 6;
            #pragma unroll
            for (int m = 0; m < 16; ++m) {
                float xv = S2[m*64 + rest];
                #pragma unroll
                for (int j = 0; j < 2; ++j)
                    acc[j] = fmaf(xv, fcS[(g*16 + m)*8 + rh*2 + j], acc[j]);
            }
            const int p = rest >> 3, q = rest & 7;
            float bpq = baS[g*8 + p] * bbS[g*8 + q];
            v0 = acc[0] + bpq * bcS[g*8 + rh*2 + 0];
            v1 = acc[1] + bpq * bcS[g*8 + rh*2 + 1];
            idx0 = rest * 8 + rh * 2;
        }
        float t = v0 + v1, t2 = v0*v0 + v1*v1;
        __syncthreads();
        #pragma unroll
        for (int off = 32; off > 0; off >>= 1) {
            t  += __shfl_down(t,  off);
            t2 += __shfl_down(t2, off);
        }
        if (lane == 0) { red[wid] = t; red[8 + wid] = t2; }
        __syncthreads();
        t  = red[0] + red[1] + red[2] + red[3];
        t2 = red[8] + red[9] + red[10] + red[11];
        float mu  = t * (1.f / 512.f);
        float var = fmaxf(t2 * (1.f / 512.f) - mu * mu, 0.f);
        float rs  = rsqrtf(var + EPSV);
        float* wp = wxo + (tb * 3 + g) * 512;
        float2 lw2 = *(const float2*)(lnow + g*512 + idx0);
        float2 lb2 = *(const float2*)(lnob + g*512 + idx0);
        float2 o2;
        o2.x = fmaf((v0 - mu) * rs, lw2.x, lb2.x);
        o2.y = fmaf((v1 - mu) * rs, lw2.y, lb2.y);
        *(float2*)(wp + idx0) = o2;
    }
}

// ============================================================
// Phase 2: sequential GRU scan. One block per batch sample n.
// 3 waves = 3 gates. h lives redundantly in each wave's regs
// (lane (p,q), regs r — identity layout preserved by the
// d->e->f contraction order). One __syncthreads per step;
// UhS parity-double-buffered. U-factors pinned in VGPRs.
// LDS XOR-swizzle (word ^= ((word>>6)&7)<<2) kills the 16-way
// conflicts on lane-stride-32B b128 accesses.
// ============================================================
__global__ __launch_bounds__(192, 1) void scan_kernel(
    const float* __restrict__ wx,     // [T*B, 3, 512]
    const float* __restrict__ h0,     // [B, 512]
    const float* __restrict__ Ufa, const float* __restrict__ Ufb,
    const float* __restrict__ Ufc,
    const float* __restrict__ Uba, const float* __restrict__ Ubb,
    const float* __restrict__ Ubc,
    const float* __restrict__ lniw, const float* __restrict__ lnib,
    const float* __restrict__ lnow, const float* __restrict__ lnob,
    float* __restrict__ out,          // [T*B, 512]
    int T, int B)
{
    const int n    = blockIdx.x;
    const int tid  = threadIdx.x;
    const int g    = tid >> 6;        // wave = gate
    const int lane = tid & 63;

    __shared__ float hgS[3][512];
    __shared__ float T1S[3][512];
    __shared__ float T2S[3][512];
    __shared__ float UhS[2][3][512];

    // ---- per-wave weights, pinned in VGPRs ----
    float f1[8][8], f2[8][8], f3[8][8];
    #pragma unroll
    for (int m = 0; m < 8; ++m)
        #pragma unroll
        for (int q = 0; q < 8; ++q) {
            f1[m][q] = Ufa[g*64 + m*8 + q]; KEEP(f1[m][q]);
            f2[m][q] = Ufb[g*64 + m*8 + q]; KEEP(f2[m][q]);
            f3[m][q] = Ufc[g*64 + m*8 + q]; KEEP(f3[m][q]);
        }
    float lnw[8], lnb[8], low[8], lob[8], ub[8];
    {
        const int p_ = lane >> 3, q_ = lane & 7;
        const float bpq = Uba[g*8 + p_] * Ubb[g*8 + q_];
        #pragma unroll
        for (int k = 0; k < 8; ++k) {
            lnw[k] = lniw[g*512 + lane*8 + k]; KEEP(lnw[k]);
            lnb[k] = lnib[g*512 + lane*8 + k]; KEEP(lnb[k]);
            low[k] = lnow[g*512 + lane*8 + k]; KEEP(low[k]);
            lob[k] = lnob[g*512 + lane*8 + k]; KEEP(lob[k]);
            ub[k]  = bpq * Ubc[g*8 + k];       KEEP(ub[k]);
        }
    }

    // ---- swizzled LDS addressing ----
    // logical word w (0..511) -> physical w ^ (((w>>6)&7)<<2)
    const int w0 = (lane*8) ^ ((lane >> 3) << 2);  // own block0 (k=0..3)
    const int w1 = w0 ^ 4;                         // own block1 (k=4..7)
    int rb[8];                                     // stage-read addrs, m=0..7
    #pragma unroll
    for (int m = 0; m < 8; ++m) rb[m] = m*64 + (lane ^ ((m & 7) << 2));

    // ---- h in regs (element lane*8+k), redundant per wave ----
    float hv[8];
    {
        const float4 a = *(const float4*)(h0 + n*512 + lane*8);
        const float4 b = *(const float4*)(h0 + n*512 + lane*8 + 4);
        hv[0]=a.x; hv[1]=a.y; hv[2]=a.z; hv[3]=a.w;
        hv[4]=b.x; hv[5]=b.y; hv[6]=b.z; hv[7]=b.w;
    }

    // ---- wx prefetch (all 3 gates, one step ahead) ----
    float pf[3][8];
    auto load_wx = [&](int t) {
        const float* base = wx + (((size_t)t * B + n) * 3) * 512 + lane*8;
        #pragma unroll
        for (int gg = 0; gg < 3; ++gg) {
            const float4 a = *(const float4*)(base + gg*512);
            const float4 b = *(const float4*)(base + gg*512 + 4);
            pf[gg][0]=a.x; pf[gg][1]=a.y; pf[gg][2]=a.z; pf[gg][3]=a.w;
            pf[gg][4]=b.x; pf[gg][5]=b.y; pf[gg][6]=b.z; pf[gg][7]=b.w;
        }
    };
    load_wx(0);

    // ---- hidden-to-hidden pipeline: h regs -> Uh (std, lnin, 3 LDS-transpose
    //      contraction stages d->e->f, rank-1 bias, std, lnout) ----
    auto pipeline = [&](float* UhOut) {
        // std(h) via DPP
        float sA = 0.f, sB = 0.f;
        #pragma unroll
        for (int k = 0; k < 8; ++k) { sA += hv[k]; sB += hv[k]*hv[k]; }
        sA = wave_allsum(sA); sB = wave_allsum(sB);
        const float mu = sA * (1.f/512.f);
        const float rs = rsqrtf(fmaxf(sB * (1.f/512.f) - mu*mu, 0.f) + EPSV);
        // lnin affine -> hgS[g] (standard layout, swizzled)
        {
            float h0_ = fmaf((hv[0]-mu)*rs, lnw[0], lnb[0]);
            float h1_ = fmaf((hv[1]-mu)*rs, lnw[1], lnb[1]);
            float h2_ = fmaf((hv[2]-mu)*rs, lnw[2], lnb[2]);
            float h3_ = fmaf((hv[3]-mu)*rs, lnw[3], lnb[3]);
            float h4_ = fmaf((hv[4]-mu)*rs, lnw[4], lnb[4]);
            float h5_ = fmaf((hv[5]-mu)*rs, lnw[5], lnb[5]);
            float h6_ = fmaf((hv[6]-mu)*rs, lnw[6], lnb[6]);
            float h7_ = fmaf((hv[7]-mu)*rs, lnw[7], lnb[7]);
            *(float4*)&hgS[g][w0] = make_float4(h0_, h1_, h2_, h3_);
            *(float4*)&hgS[g][w1] = make_float4(h4_, h5_, h6_, h7_);
        }
        // stage A: contract d -> p    [d,e,f] -> [(e,f),p]
        {
            float a[8] = {0,0,0,0,0,0,0,0};
            #pragma unroll
            for (int m = 0; m < 8; ++m) {
                const float xv = hgS[g][rb[m]];
                #pragma unroll
                for (int q = 0; q < 8; ++q) a[q] = fmaf(xv, f1[m][q], a[q]);
            }
            *(float4*)&T1S[g][w0] = make_float4(a[0], a[1], a[2], a[3]);
            *(float4*)&T1S[g][w1] = make_float4(a[4], a[5], a[6], a[7]);
        }
        // stage B: contract e -> q    [(e,f),p] -> [(f,p),q]
        {
            float a[8] = {0,0,0,0,0,0,0,0};
            #pragma unroll
            for (int m = 0; m < 8; ++m) {
                const float xv = T1S[g][rb[m]];
                #pragma unroll
                for (int q = 0; q < 8; ++q) a[q] = fmaf(xv, f2[m][q], a[q]);
            }
            *(float4*)&T2S[g][w0] = make_float4(a[0], a[1], a[2], a[3]);
            *(float4*)&T2S[g][w1] = make_float4(a[4], a[5], a[6], a[7]);
        }
        // stage C: contract f -> r    [(f,p),q] -> [(p,q),r]  == identity layout
        float a[8] = {0,0,0,0,0,0,0,0};
        #pragma unroll
        for (int m = 0; m < 8; ++m) {
            const float xv = T2S[g][rb[m]];
            #pragma unroll
            for (int r = 0; r < 8; ++r) a[r] = fmaf(xv, f3[m][r], a[r]);
        }
        // + rank-1 bias, std, lnout
        float sC = 0.f, sD = 0.f;
        #pragma unroll
        for (int k = 0; k < 8; ++k) { a[k] += ub[k]; sC += a[k]; sD += a[k]*a[k]; }
        sC = wave_allsum(sC); sD = wave_allsum(sD);
        const float mu2 = sC * (1.f/512.f);
        const float rs2 = rsqrtf(fmaxf(sD * (1.f/512.f) - mu2*mu2, 0.f) + EPSV);
        float u0_ = fmaf((a[0]-mu2)*rs2, low[0], lob[0]);
        float u1_ = fmaf((a[1]-mu2)*rs2, low[1], lob[1]);
        float u2_ = fmaf((a[2]-mu2)*rs2, low[2], lob[2]);
        float u3_ = fmaf((a[3]-mu2)*rs2, low[3], lob[3]);
        float u4_ = fmaf((a[4]-mu2)*rs2, low[4], lob[4]);
        float u5_ = fmaf((a[5]-mu2)*rs2, low[5], lob[5]);
        float u6_ = fmaf((a[6]-mu2)*rs2, low[6], lob[6]);
        float u7_ = fmaf((a[7]-mu2)*rs2, low[7], lob[7]);
        *(float4*)&UhOut[w0] = make_float4(u0_, u1_, u2_, u3_);
        *(float4*)&UhOut[w1] = make_float4(u4_, u5_, u6_, u7_);
    };

    // prologue: Uh(h0) into parity 0
    pipeline(&UhS[0][g][0]);

    int par = 0;
    for (int t = 0; t < T; ++t) {
        __syncthreads();   // UhS[par] (all 3 planes) ready
        // ---- combine: h = GRU(wx(t), Uh(t), h) — redundant in every wave ----
        float u[3][8];
        #pragma unroll
        for (int gg = 0; gg < 3; ++gg) {
            const float4 a = *(const float4*)&UhS[par][gg][w0];
            const float4 b = *(const float4*)&UhS[par][gg][w1];
            u[gg][0]=a.x; u[gg][1]=a.y; u[gg][2]=a.z; u[gg][3]=a.w;
            u[gg][4]=b.x; u[gg][5]=b.y; u[gg][6]=b.z; u[gg][7]=b.w;
        }
        #pragma unroll
        for (int k = 0; k < 8; ++k) {
            const float r  = 1.f / (1.f + __expf(-(pf[0][k] + u[0][k])));
            const float z  = 1.f / (1.f + __expf(-(pf[1][k] + u[1][k])));
            const float e2 = __expf(2.f * (pf[2][k] + r * u[2][k]));
            const float nn = 1.f - 2.f / (e2 + 1.f);   // tanh, saturation-safe
            hv[k] = (1.f - z) * nn + z * hv[k];
        }
        if (g == 0) {
            float* op = out + ((size_t)t * B + n) * 512 + lane*8;
            *(float4*)op     = make_float4(hv[0], hv[1], hv[2], hv[3]);
            *(float4*)(op+4) = make_float4(hv[4], hv[5], hv[6], hv[7]);
        }
        if (t + 1 < T) {
            load_wx(t + 1);                 // issue-early; consumed next step
            pipeline(&UhS[par ^ 1][g][0]);  // Uh(h_{t+1}) into other parity
        }
        par ^= 1;
    }
}

extern "C" void kernel_launch(void* const* d_in, const int* in_sizes, int n_in,
                              void* d_out, int out_size, void* d_ws, size_t ws_size,
                              hipStream_t stream)
{
    const float* x    = (const float*)d_in[0];
    const float* h0   = (const float*)d_in[1];
    const float* Wfa  = (const float*)d_in[2];
    const float* Wfb  = (const float*)d_in[3];
    const float* Wfc  = (const float*)d_in[4];
    const float* Wba  = (const float*)d_in[5];
    const float* Wbb  = (const float*)d_in[6];
    const float* Wbc  = (const float*)d_in[7];
    const float* Wliw = (const float*)d_in[8];
    const float* Wlib = (const float*)d_in[9];
    const float* Wlow = (const float*)d_in[10];
    const float* Wlob = (const float*)d_in[11];
    const float* Ufa  = (const float*)d_in[12];
    const float* Ufb  = (const float*)d_in[13];
    const float* Ufc  = (const float*)d_in[14];
    const float* Uba  = (const float*)d_in[15];
    const float* Ubb  = (const float*)d_in[16];
    const float* Ubc  = (const float*)d_in[17];
    const float* Uliw = (const float*)d_in[18];
    const float* Ulib = (const float*)d_in[19];
    const float* Ulow = (const float*)d_in[20];
    const float* Ulob = (const float*)d_in[21];

    const int B = in_sizes[1] / 512;            // 16
    const int T = in_sizes[0] / (B * 4096);     // 512

    float* wxws = (float*)d_ws;                 // [T*B, 3, 512] scratch
    float* out  = (float*)d_out;

    wx_kernel<<<T * B, 256, 0, stream>>>(x, Wfa, Wfb, Wfc, Wba, Wbb, Wbc,
                                         Wliw, Wlib, Wlow, Wlob, wxws);
    scan_kernel<<<B, 192, 0, stream>>>(wxws, h0, Ufa, Ufb, Ufc, Uba, Ubb, Ubc,
                                       Uliw, Ulib, Ulow, Ulob, out, T, B);
}